// Round 11
// baseline (119.060 us; speedup 1.0000x reference)
//
#include <hip/hip_runtime.h>

#define K_CW 256
#define PPT 4       // points per thread
#define NQ 4        // split-K quarters
#define KQ (K_CW / NQ)  // 64 k per quarter

// Build packed codebook in ws: per k, 8 floats {c0,c1,c2,c3, csq,0,0,0} (32 B).
// csq uses numpy rounding: ((c0*c0 + c1*c1) + c2*c2) + c3*c3
__global__ void vq_pack_kernel(const float* __restrict__ tlut, float* __restrict__ pk) {
    int k = threadIdx.x;  // 256 threads, 1 block
    float c0 = tlut[k * 4 + 0];
    float c1 = tlut[k * 4 + 1];
    float c2 = tlut[k * 4 + 2];
    float c3 = tlut[k * 4 + 3];
    float s = __fadd_rn(__fadd_rn(__fadd_rn(__fmul_rn(c0, c0), __fmul_rn(c1, c1)),
                                  __fmul_rn(c2, c2)),
                        __fmul_rn(c3, c3));
    pk[k * 8 + 0] = c0; pk[k * 8 + 1] = c1; pk[k * 8 + 2] = c2; pk[k * 8 + 3] = c3;
    pk[k * 8 + 4] = s;  pk[k * 8 + 5] = 0.f; pk[k * 8 + 6] = 0.f; pk[k * 8 + 7] = 0.f;
}

__global__ __launch_bounds__(1024, 8) void vq_argmin_kernel(
    const float* __restrict__ X,
    const float* __restrict__ tlut,
    const float* __restrict__ pk,
    float* __restrict__ outX,   // [B,4] reconstruction
    float* __restrict__ outS,   // [B] state, stored as float
    int B) {
    // R7 skeleton (split-K x4, PPT=4, 32 waves/CU, 2 generations) with ONE
    // change: codebook fetch via LDS broadcast instead of s_load. Uniform
    // address -> conflict-free broadcast; unrolled -> ds_read_b128/b32 with
    // immediate offsets off a single base VGPR (zero per-k address VALU).
    __shared__ float cbf[8 * K_CW];  // 8 KB packed codebook
    __shared__ float4 sd[3 * 256];   // quarters 1..3 bestd (12 KB)
    __shared__ int4   si[3 * 256];   // quarters 1..3 besti (12 KB)

    const int t = threadIdx.x;
    if (t < 8 * K_CW / 4) {  // 512 threads stage 2048 floats as float4
        reinterpret_cast<float4*>(cbf)[t] = reinterpret_cast<const float4*>(pk)[t];
    }
    __syncthreads();

    const int tt = t & 255;
    const int q = t >> 8;  // wave-uniform (wave = 64 consecutive threads)
    const int kbase = __builtin_amdgcn_readfirstlane(q << 6);

    const int g = blockIdx.x * 256 + tt;   // point-group id
    const int stride = B / PPT;            // strided points -> coalesced

    const float4* __restrict__ X4 = reinterpret_cast<const float4*>(X);
    const float4* __restrict__ T4 = reinterpret_cast<const float4*>(tlut);

    float x0[PPT], x1[PPT], x2[PPT], x3[PPT], xsq[PPT], bestd[PPT];
    int besti[PPT];

    #pragma unroll
    for (int i = 0; i < PPT; ++i) {
        const float4 xv = X4[g + i * stride];
        x0[i] = xv.x; x1[i] = xv.y; x2[i] = xv.z; x3[i] = xv.w;
        // x_sq with numpy rounding: sequential adds of rounded squares
        xsq[i] = __fadd_rn(__fadd_rn(__fadd_rn(__fmul_rn(xv.x, xv.x), __fmul_rn(xv.y, xv.y)),
                                     __fmul_rn(xv.z, xv.z)),
                           __fmul_rn(xv.w, xv.w));
        bestd[i] = __builtin_inff();
        besti[i] = kbase;
    }

    #pragma unroll 16
    for (int kk = 0; kk < KQ; ++kk) {
        const int k = kbase + kk;
        // uniform-address LDS reads: broadcast, immediate offsets under unroll
        const float4 c = *reinterpret_cast<const float4*>(&cbf[8 * k]);
        const float cs = cbf[8 * k + 4];
        #pragma unroll
        for (int i = 0; i < PPT; ++i) {
            // cross: numpy einsum `accum += a*b` with fp-contract -> ascending FMA chain
            float cross = __fmul_rn(x0[i], c.x);
            cross = __fmaf_rn(x1[i], c.y, cross);
            cross = __fmaf_rn(x2[i], c.z, cross);
            cross = __fmaf_rn(x3[i], c.w, cross);
            // (x_sq - 2*cross) + c_sq ; fma(-2,cross,xsq) == rn(xsq - rn(2*cross)) exactly
            float t2 = __fmaf_rn(-2.0f, cross, xsq[i]);
            float d = __fadd_rn(t2, cs);
            // argmin, first occurrence (strict <), ascending k:
            // index via cmp+cndmask, value via v_min (independent ops)
            besti[i] = (d < bestd[i]) ? k : besti[i];
            bestd[i] = fminf(d, bestd[i]);
        }
    }

    if (q > 0) {
        sd[(q - 1) * 256 + tt] = make_float4(bestd[0], bestd[1], bestd[2], bestd[3]);
        si[(q - 1) * 256 + tt] = make_int4(besti[0], besti[1], besti[2], besti[3]);
    }
    __syncthreads();
    if (q == 0) {
        // merge quarters ascending in k; strict '<' -> smaller k wins ties
        // (np.argmin first-occurrence)
        #pragma unroll
        for (int j = 0; j < 3; ++j) {
            const float4 od = sd[j * 256 + tt];
            const int4   oi = si[j * 256 + tt];
            if (od.x < bestd[0]) { bestd[0] = od.x; besti[0] = oi.x; }
            if (od.y < bestd[1]) { bestd[1] = od.y; besti[1] = oi.y; }
            if (od.z < bestd[2]) { bestd[2] = od.z; besti[2] = oi.z; }
            if (od.w < bestd[3]) { bestd[3] = od.w; besti[3] = oi.w; }
        }
        #pragma unroll
        for (int i = 0; i < PPT; ++i) {
            const int p = g + i * stride;
            reinterpret_cast<float4*>(outX)[p] = T4[besti[i]];
            outS[p] = (float)besti[i];
        }
    }
}

extern "C" void kernel_launch(void* const* d_in, const int* in_sizes, int n_in,
                              void* d_out, int out_size, void* d_ws, size_t ws_size,
                              hipStream_t stream) {
    const float* X    = (const float*)d_in[0];   // [B,4]
    const float* tlut = (const float*)d_in[1];   // [256,4]
    const int B = in_sizes[0] / 4;

    float* outX = (float*)d_out;          // first B*4 floats: hatX
    float* outS = outX + (size_t)B * 4;   // next B floats: state (as float)

    float* pk = (float*)d_ws;             // 256*8 floats packed codebook

    vq_pack_kernel<<<1, 256, 0, stream>>>(tlut, pk);

    const int groups = B / PPT;           // 262144 point-groups
    const int grid = groups / 256;        // 1024 blocks of 1024 threads
    vq_argmin_kernel<<<grid, 1024, 0, stream>>>(X, tlut, pk, outX, outS, B);
}

// Round 12
// 116.371 us; speedup vs baseline: 1.0231x; 1.0231x over previous
//
#include <hip/hip_runtime.h>

#define K_CW 256
#define PPT 4       // points per thread
#define NQ 4        // split-K quarters
#define KQ (K_CW / NQ)  // 64 k per quarter == wave width

__global__ __launch_bounds__(1024, 8) void vq_argmin_kernel(
    const float* __restrict__ X,
    const float* __restrict__ tlut,
    float* __restrict__ outX,   // [B,4] reconstruction
    float* __restrict__ outS,   // [B] state, stored as float
    int B) {
    // R7 skeleton (split-K x4, PPT=4, 1024-thr blocks, 32 waves/CU) with the
    // per-iter fetch slimmed: codeword via s_load_dwordx4 of tlut directly;
    // csq held per-LANE (lane j owns csq[kbase+j]) and broadcast per iter via
    // v_readlane -> 1 VALU op, zero memory traffic, no lgkm wait. Single
    // kernel launch (pack kernel eliminated).
    __shared__ float4 sd[3 * 256];   // quarters 1..3 bestd (12 KB)
    __shared__ int4   si[3 * 256];   // quarters 1..3 besti (12 KB)

    const int t = threadIdx.x;
    const int tt = t & 255;
    const int q = t >> 8;  // wave-uniform (wave = 64 consecutive threads)
    const int kbase = __builtin_amdgcn_readfirstlane(q << 6);
    const int lane = t & 63;

    const float4* __restrict__ X4 = reinterpret_cast<const float4*>(X);
    const float4* __restrict__ T4 = reinterpret_cast<const float4*>(tlut);

    // lane j precomputes csq for k = kbase + j with numpy rounding:
    // ((c0*c0 + c1*c1) + c2*c2) + c3*c3  (sequential adds of rounded squares)
    float vcsq;
    {
        const float4 cl = T4[kbase + lane];   // coalesced 64-entry read
        vcsq = __fadd_rn(__fadd_rn(__fadd_rn(__fmul_rn(cl.x, cl.x), __fmul_rn(cl.y, cl.y)),
                                   __fmul_rn(cl.z, cl.z)),
                         __fmul_rn(cl.w, cl.w));
    }

    const int g = blockIdx.x * 256 + tt;   // point-group id
    const int stride = B / PPT;            // strided points -> coalesced

    float x0[PPT], x1[PPT], x2[PPT], x3[PPT], xsq[PPT], bestd[PPT];
    int besti[PPT];

    #pragma unroll
    for (int i = 0; i < PPT; ++i) {
        const float4 xv = X4[g + i * stride];
        x0[i] = xv.x; x1[i] = xv.y; x2[i] = xv.z; x3[i] = xv.w;
        // x_sq with numpy rounding: sequential adds of rounded squares
        xsq[i] = __fadd_rn(__fadd_rn(__fadd_rn(__fmul_rn(xv.x, xv.x), __fmul_rn(xv.y, xv.y)),
                                     __fmul_rn(xv.z, xv.z)),
                           __fmul_rn(xv.w, xv.w));
        bestd[i] = __builtin_inff();
        besti[i] = kbase;
    }

    #pragma unroll 16
    for (int kk = 0; kk < KQ; ++kk) {
        const int k = kbase + kk;          // wave-uniform -> scalar path
        const float4 c = T4[k];            // one s_load_dwordx4 per k
        // csq broadcast from owning lane: exact bits, no memory op
        const float cs = __int_as_float(
            __builtin_amdgcn_readlane(__float_as_int(vcsq), kk));
        #pragma unroll
        for (int i = 0; i < PPT; ++i) {
            // cross: numpy einsum `accum += a*b` with fp-contract -> ascending FMA chain
            float cross = __fmul_rn(x0[i], c.x);
            cross = __fmaf_rn(x1[i], c.y, cross);
            cross = __fmaf_rn(x2[i], c.z, cross);
            cross = __fmaf_rn(x3[i], c.w, cross);
            // (x_sq - 2*cross) + c_sq ; fma(-2,cross,xsq) == rn(xsq - rn(2*cross)) exactly
            float t2 = __fmaf_rn(-2.0f, cross, xsq[i]);
            float d = __fadd_rn(t2, cs);
            // argmin, first occurrence (strict <), ascending k:
            // index via cmp+cndmask, value via v_min (independent ops)
            besti[i] = (d < bestd[i]) ? k : besti[i];
            bestd[i] = fminf(d, bestd[i]);
        }
    }

    if (q > 0) {
        sd[(q - 1) * 256 + tt] = make_float4(bestd[0], bestd[1], bestd[2], bestd[3]);
        si[(q - 1) * 256 + tt] = make_int4(besti[0], besti[1], besti[2], besti[3]);
    }
    __syncthreads();
    if (q == 0) {
        // merge quarters ascending in k; strict '<' -> smaller k wins ties
        // (np.argmin first-occurrence)
        #pragma unroll
        for (int j = 0; j < 3; ++j) {
            const float4 od = sd[j * 256 + tt];
            const int4   oi = si[j * 256 + tt];
            if (od.x < bestd[0]) { bestd[0] = od.x; besti[0] = oi.x; }
            if (od.y < bestd[1]) { bestd[1] = od.y; besti[1] = oi.y; }
            if (od.z < bestd[2]) { bestd[2] = od.z; besti[2] = oi.z; }
            if (od.w < bestd[3]) { bestd[3] = od.w; besti[3] = oi.w; }
        }
        #pragma unroll
        for (int i = 0; i < PPT; ++i) {
            const int p = g + i * stride;
            reinterpret_cast<float4*>(outX)[p] = T4[besti[i]];
            outS[p] = (float)besti[i];
        }
    }
}

extern "C" void kernel_launch(void* const* d_in, const int* in_sizes, int n_in,
                              void* d_out, int out_size, void* d_ws, size_t ws_size,
                              hipStream_t stream) {
    const float* X    = (const float*)d_in[0];   // [B,4]
    const float* tlut = (const float*)d_in[1];   // [256,4]
    const int B = in_sizes[0] / 4;

    float* outX = (float*)d_out;          // first B*4 floats: hatX
    float* outS = outX + (size_t)B * 4;   // next B floats: state (as float)

    const int groups = B / PPT;           // 262144 point-groups
    const int grid = groups / 256;        // 1024 blocks of 1024 threads
    vq_argmin_kernel<<<grid, 1024, 0, stream>>>(X, tlut, outX, outS, B);
}